// Round 15
// baseline (150.144 us; speedup 1.0000x reference)
//
#include <hip/hip_runtime.h>
#include <stdint.h>

#define M_DIM 8192   // K of the Gram GEMM
#define N_DIM 4096   // output N x N

typedef __attribute__((ext_vector_type(4))) int i32x4;
typedef __attribute__((ext_vector_type(8))) int i32x8;
typedef __attribute__((ext_vector_type(16))) float f32x16;

// fp32 -> OCP e4m3 (RNE, FTZ below 2^-6, saturate to 448)
__device__ __forceinline__ unsigned char f2e4m3(float x) {
  union { float f; uint32_t u; } v;
  v.f = x;
  const uint32_t s = (v.u >> 24) & 0x80;
  const uint32_t au = v.u & 0x7fffffffu;
  if (au < 0x3c800000u) return (unsigned char)s;  // |x| < 2^-6 -> 0
  const uint32_t r = au + 0x7ffffu + ((au >> 20) & 1u);  // RNE at 3 mantissa bits
  int e = (int)(r >> 23) - 127;
  uint32_t m = (r >> 20) & 7u;
  if (e > 8 || (e == 8 && m == 7)) { e = 8; m = 6; }  // sat 448, avoid NaN
  return (unsigned char)(s | ((uint32_t)(e + 7) << 3) | m);
}

__device__ __forceinline__ void gl_lds16b(const char* g, char* l) {
  __builtin_amdgcn_global_load_lds(
      (const __attribute__((address_space(1))) void*)g,
      (__attribute__((address_space(3))) void*)l, 16, 0, 0);
}

#define CFENCE asm volatile("" ::: "memory")

// ---------------- Kernel 1: A[M][N] fp32 -> At packed operand-major fp8.
// At layout: [nblk(16)][kc(128)][g(8)][c(4)][r32(32)][byte e(16)]
//   element (n, k): nblk=n>>8, kc=k>>6, g=(n>>5)&7, c=(k>>4)&3, r32=n&31, e=k&15
// 16KB per (nblk,kc); a 128-col half-panel = contiguous 8KB half of a block.
__global__ __launch_bounds__(256) void transpose_pack_fp8(
    const float* __restrict__ A, unsigned char* __restrict__ At) {
  __shared__ unsigned char tile[64][68];  // tile[x][y] = A[m0+y][n0+x]
  const int bm = blockIdx.x % (M_DIM / 64);
  const int bn = blockIdx.x / (M_DIM / 64);
  const int m0 = bm * 64, n0 = bn * 64;
  const int t = threadIdx.x;
  const int tr = t >> 4;
  const int tc = (t & 15) << 2;
#pragma unroll
  for (int p = 0; p < 4; ++p) {
    const int r = p * 16 + tr;  // m_local
    const float4 v = *reinterpret_cast<const float4*>(
        &A[(size_t)(m0 + r) * N_DIM + (n0 + tc)]);
    tile[tc + 0][r] = f2e4m3(v.x);
    tile[tc + 1][r] = f2e4m3(v.y);
    tile[tc + 2][r] = f2e4m3(v.z);
    tile[tc + 3][r] = f2e4m3(v.w);
  }
  __syncthreads();
  const int cC = (tc >> 4) & 3;   // k-chunk within 64
  const int eC = tc & 15;         // byte within 16B chunk
  const int nblk = n0 >> 8;
  const int kc = m0 >> 6;
  unsigned char* const obase = At + ((size_t)(nblk * 128 + kc) * 8) * 2048;
#pragma unroll
  for (int p = 0; p < 4; ++p) {
    const int rn = p * 16 + tr;       // n_local
    const int n = n0 + rn;
    const int g = (n >> 5) & 7;
    const int r32 = n & 31;
    uchar4 o;
    o.x = tile[rn][tc + 0];  // k = m0+tc+0 .. +3
    o.y = tile[rn][tc + 1];
    o.z = tile[rn][tc + 2];
    o.w = tile[rn][tc + 3];
    *reinterpret_cast<uchar4*>(
        &obase[g * 2048 + cC * 512 + r32 * 16 + eC]) = o;
  }
}

// ---------------- Kernel 2: 256x128 blocks, 2 blocks/CU (de-lockstepped),
// 4 waves (2x2, wave 128x64), MX-scaled mfma_scale_f32_32x32x64_f8f6f4
// (unit scales). 3 LDS bufs x 24KB (A 16KB @0, B 8KB @16384) = 72KB/block,
// stage chunk S+2, counted vmcnt(6), one barrier/iter. Packed layout: all
// LDS reads contiguous 512B regions (0 conflicts, verified R11/R14).
__global__ __launch_bounds__(256, 2) void gram_fp8s(
    const unsigned char* __restrict__ At, float* __restrict__ C) {
  __shared__ char smem[73728];  // 3 x 24KB

  const int bid = (int)blockIdx.x;
  const int wg = (bid & 7) * 64 + (bid >> 3);  // XCD swizzle (512 % 8 == 0)
  const int bi = wg >> 5, bj = wg & 31;        // 16 row-panels x 32 col-panels

  const int t = (int)threadIdx.x;
  const int lane = t & 63, wave = t >> 6;
  const int wr = wave >> 1, wc = wave & 1;     // wave tile 128x64
  const int l31 = lane & 31, hi = lane >> 5;

  // operand read addresses within a 24KB buffer
  int adA[4], adB[2];
#pragma unroll
  for (int mb = 0; mb < 4; ++mb)
    adA[mb] = (wr * 4 + mb) * 2048 + hi * 1024 + l31 * 16;
#pragma unroll
  for (int nb = 0; nb < 2; ++nb)
    adB[nb] = 16384 + (wc * 2 + nb) * 2048 + hi * 1024 + l31 * 16;

  // staging sources (plain linear; packed layout == LDS layout)
  const char* const Atb = (const char*)At;
  const char* const sAc = Atb + (size_t)bi * (128 * 16384);
  const char* const sBc = Atb + (size_t)(bj >> 1) * (128 * 16384) + (bj & 1) * 8192;
  const int dd = t * 16;  // 0..4080

  f32x16 acc[4][2] = {};

  // prologue: stage chunks 0,1 into bufs 0,1 (6 gl_lds each: A 4, B 2)
#pragma unroll
  for (int ss = 0; ss < 2; ++ss) {
    char* const b = smem + ss * 24576;
    const size_t ko = (size_t)ss * 16384;
#pragma unroll
    for (int i = 0; i < 4; ++i)
      gl_lds16b(sAc + ko + i * 4096 + dd, b + i * 4096 + dd);
#pragma unroll
    for (int i = 0; i < 2; ++i)
      gl_lds16b(sBc + ko + i * 4096 + dd, b + 16384 + i * 4096 + dd);
  }

#define ITER(S, P, Q, STG, VMW) do {                                         \
  if ((VMW) == 6)      asm volatile("s_waitcnt vmcnt(6)" ::: "memory");      \
  else if ((VMW) == 0) asm volatile("s_waitcnt vmcnt(0)" ::: "memory");      \
  __builtin_amdgcn_s_barrier();                                              \
  CFENCE;                                                                    \
  {                                                                          \
    const char* const bb = smem + (P) * 24576;                               \
    i32x8 av[4], bv[2];                                                      \
    _Pragma("unroll") for (int mb = 0; mb < 4; ++mb) {                       \
      const i32x4 lo = *reinterpret_cast<const i32x4*>(bb + adA[mb]);        \
      const i32x4 hv = *reinterpret_cast<const i32x4*>(bb + adA[mb] + 512);  \
      av[mb] = __builtin_shufflevector(lo, hv, 0, 1, 2, 3, 4, 5, 6, 7);      \
    }                                                                        \
    _Pragma("unroll") for (int nb = 0; nb < 2; ++nb) {                       \
      const i32x4 lo = *reinterpret_cast<const i32x4*>(bb + adB[nb]);        \
      const i32x4 hv = *reinterpret_cast<const i32x4*>(bb + adB[nb] + 512);  \
      bv[nb] = __builtin_shufflevector(lo, hv, 0, 1, 2, 3, 4, 5, 6, 7);      \
    }                                                                        \
    if (STG) {                                                               \
      char* const sbf = smem + (Q) * 24576;                                  \
      const size_t ko = (size_t)((S) + 2) * 16384;                           \
      _Pragma("unroll") for (int i = 0; i < 4; ++i)                          \
        gl_lds16b(sAc + ko + i * 4096 + dd, sbf + i * 4096 + dd);            \
      _Pragma("unroll") for (int i = 0; i < 2; ++i)                          \
        gl_lds16b(sBc + ko + i * 4096 + dd, sbf + 16384 + i * 4096 + dd);    \
    }                                                                        \
    __builtin_amdgcn_s_setprio(1);                                           \
    _Pragma("unroll") for (int mb = 0; mb < 4; ++mb)                         \
      _Pragma("unroll") for (int nb = 0; nb < 2; ++nb)                       \
        acc[mb][nb] = __builtin_amdgcn_mfma_scale_f32_32x32x64_f8f6f4(       \
            av[mb], bv[nb], acc[mb][nb], 0, 0,                               \
            0, 0x7F7F7F7F, 0, 0x7F7F7F7F);                                   \
    __builtin_amdgcn_s_setprio(0);                                           \
  }                                                                          \
} while (0)

  // 128 K-chunks of 64; stage chunk S+2 in iters 0..125
  for (int s = 0; s < 126; s += 3) {
    ITER(s + 0, 0, 2, true, 6);
    ITER(s + 1, 1, 0, true, 6);
    ITER(s + 2, 2, 1, true, 6);
  }
  ITER(126, 0, -1, false, 6);
  ITER(127, 1, -1, false, 0);

#undef ITER

  // epilogue: 32x32 C/D map (verified R6/R9/R11): col = lane&31,
  // row = (reg&3) + 8*(reg>>2) + 4*(lane>>5)
  const int rb = bi * 256 + wr * 128;
  const int cb = bj * 128 + wc * 64;
#pragma unroll
  for (int mb = 0; mb < 4; ++mb) {
#pragma unroll
    for (int nb = 0; nb < 2; ++nb) {
      const int c = cb + nb * 32 + l31;
#pragma unroll
      for (int rg = 0; rg < 4; ++rg) {
        const int r0 = rb + mb * 32 + rg * 8 + hi * 4;
#pragma unroll
        for (int j = 0; j < 4; ++j)
          C[(size_t)(r0 + j) * N_DIM + c] = acc[mb][nb][rg * 4 + j];
      }
    }
  }
}

extern "C" void kernel_launch(void* const* d_in, const int* in_sizes, int n_in,
                              void* d_out, int out_size, void* d_ws, size_t ws_size,
                              hipStream_t stream) {
  const float* A = (const float*)d_in[0];
  float* C = (float*)d_out;
  unsigned char* At = (unsigned char*)d_ws;  // 32 MiB packed

  transpose_pack_fp8<<<dim3((M_DIM / 64) * (N_DIM / 64)), 256, 0, stream>>>(A, At);
  gram_fp8s<<<dim3(512), 256, 0, stream>>>(At, C);
}